// Round 3
// baseline (3024.354 us; speedup 1.0000x reference)
//
#include <hip/hip_runtime.h>

namespace {

constexpr int kNIn = 128;
constexpr int kNRec = 128;
constexpr int BR = 64;              // rows per block
constexpr int KC = 32;              // k-chunk staged in LDS
constexpr int NCH = kNIn / KC;      // 4 chunks

__device__ __forceinline__ float fcomp(const float4 f, int i) {
  switch (i & 3) {
    case 0: return f.x;
    case 1: return f.y;
    case 2: return f.z;
    default: return f.w;
  }
}

// Block: 256 threads, tile 64 rows x 128 cols; thread tile 4 rows x 8 cols
// (cols c0..c0+3 and c0+64..c0+67: LDS weight reads are 16 contiguous
// lanes x 16B = 2-way bank aliasing = free, m136).
// Weights staged in LDS in k-chunks of 32 (2 x 16 KB = 32 KB).
// Explicit software pipeline: A-operands double-buffered one k-quad ahead;
// next chunk's weights prefetched into registers at chunk START (whole
// chunk's compute covers their latency) and committed to LDS at the
// boundary. Plain float4 stores — nontemporal stores measured 2.33x write
// amplification on gfx950 (R2: 448 MiB vs 192 MiB ideal).
// GEMM accumulates with sequential-k FMA in fp32 (merged x/z streams);
// epilogue uses explicit IEEE intrinsics to mirror numpy ops.
__global__ __launch_bounds__(256, 4) void lif_fused(
    const float* __restrict__ x, const float* __restrict__ z,
    const float* __restrict__ v, const float* __restrict__ t,
    const float* __restrict__ w_in, const float* __restrict__ w_rec,
    float* __restrict__ out, int batch) {
  __shared__ float swi[KC][kNRec];
  __shared__ float swr[KC][kNRec];

  const int tid = threadIdx.x;
  const int tc = tid & 15;          // 16 col groups
  const int tr = tid >> 4;          // 16 row groups x 4 rows = 64 rows
  const int row0 = blockIdx.x * BR + tr * 4;
  const int c0 = tc * 4;

  float acc[4][8];
#pragma unroll
  for (int i = 0; i < 4; ++i)
#pragma unroll
    for (int c = 0; c < 8; ++c) acc[i][c] = 0.0f;

  const float4* __restrict__ x4 =
      reinterpret_cast<const float4*>(x) + (size_t)row0 * (kNIn / 4);
  const float4* __restrict__ z4 =
      reinterpret_cast<const float4*>(z) + (size_t)row0 * (kNRec / 4);
  const float4* __restrict__ gwi = reinterpret_cast<const float4*>(w_in);
  const float4* __restrict__ gwr = reinterpret_cast<const float4*>(w_rec);
  float4* swi4 = reinterpret_cast<float4*>(&swi[0][0]);
  float4* swr4 = reinterpret_cast<float4*>(&swr[0][0]);

  // ---- Stage chunk 0 weights ----
  float4 wa[4], wb[4];
#pragma unroll
  for (int j = 0; j < 4; ++j) {
    wa[j] = gwi[tid + 256 * j];
    wb[j] = gwr[tid + 256 * j];
  }
#pragma unroll
  for (int j = 0; j < 4; ++j) {
    swi4[tid + 256 * j] = wa[j];
    swr4[tid + 256 * j] = wb[j];
  }
  __syncthreads();

  // ---- Prime A pipeline (k-quad 0) ----
  float4 axc[4], azc[4], axn[4], azn[4];
#pragma unroll
  for (int i = 0; i < 4; ++i) {
    axc[i] = x4[(size_t)i * (kNIn / 4)];
    azc[i] = z4[(size_t)i * (kNRec / 4)];
  }

  for (int ch = 0; ch < NCH; ++ch) {
    // Prefetch NEXT chunk's weights into registers now; the entire chunk's
    // compute (~2000 cycles) covers their global latency.
    if (ch != NCH - 1) {
      const float4* ngwi = gwi + (size_t)(ch + 1) * KC * (kNRec / 4);
      const float4* ngwr = gwr + (size_t)(ch + 1) * KC * (kNRec / 4);
#pragma unroll
      for (int j = 0; j < 4; ++j) {
        wa[j] = ngwi[tid + 256 * j];
        wb[j] = ngwr[tid + 256 * j];
      }
    }

#pragma unroll
    for (int kq = 0; kq < KC / 4; ++kq) {
      // Prefetch A for the next k-quad (clamped: last iteration redundantly
      // reloads kg=31 — branch-free, values unused).
      int kgn = ch * (KC / 4) + kq + 1;
      kgn = kgn < (kNIn / 4) ? kgn : (kNIn / 4) - 1;
#pragma unroll
      for (int i = 0; i < 4; ++i) {
        axn[i] = x4[(size_t)i * (kNIn / 4) + kgn];
        azn[i] = z4[(size_t)i * (kNRec / 4) + kgn];
      }

#pragma unroll
      for (int kk = 0; kk < 4; ++kk) {
        const int k = kq * 4 + kk;
        const float4 wi0 = *reinterpret_cast<const float4*>(&swi[k][c0]);
        const float4 wi1 = *reinterpret_cast<const float4*>(&swi[k][c0 + 64]);
        const float4 wr0 = *reinterpret_cast<const float4*>(&swr[k][c0]);
        const float4 wr1 = *reinterpret_cast<const float4*>(&swr[k][c0 + 64]);
#pragma unroll
        for (int i = 0; i < 4; ++i) {
          const float a = fcomp(axc[i], kk);
          const float b = fcomp(azc[i], kk);
          acc[i][0] = __fmaf_rn(a, wi0.x, acc[i][0]);
          acc[i][1] = __fmaf_rn(a, wi0.y, acc[i][1]);
          acc[i][2] = __fmaf_rn(a, wi0.z, acc[i][2]);
          acc[i][3] = __fmaf_rn(a, wi0.w, acc[i][3]);
          acc[i][4] = __fmaf_rn(a, wi1.x, acc[i][4]);
          acc[i][5] = __fmaf_rn(a, wi1.y, acc[i][5]);
          acc[i][6] = __fmaf_rn(a, wi1.z, acc[i][6]);
          acc[i][7] = __fmaf_rn(a, wi1.w, acc[i][7]);
          acc[i][0] = __fmaf_rn(b, wr0.x, acc[i][0]);
          acc[i][1] = __fmaf_rn(b, wr0.y, acc[i][1]);
          acc[i][2] = __fmaf_rn(b, wr0.z, acc[i][2]);
          acc[i][3] = __fmaf_rn(b, wr0.w, acc[i][3]);
          acc[i][4] = __fmaf_rn(b, wr1.x, acc[i][4]);
          acc[i][5] = __fmaf_rn(b, wr1.y, acc[i][5]);
          acc[i][6] = __fmaf_rn(b, wr1.z, acc[i][6]);
          acc[i][7] = __fmaf_rn(b, wr1.w, acc[i][7]);
        }
      }

      // Rotate A pipeline.
#pragma unroll
      for (int i = 0; i < 4; ++i) {
        axc[i] = axn[i];
        azc[i] = azn[i];
      }
    }

    // Commit prefetched weights for the next chunk.
    if (ch != NCH - 1) {
      __syncthreads();  // prior chunk's readers done
#pragma unroll
      for (int j = 0; j < 4; ++j) {
        swi4[tid + 256 * j] = wa[j];
        swr4[tid + 256 * j] = wb[j];
      }
      __syncthreads();
    }
  }

  // decay**e table, e in [0,7]: t in [0,4] -> exponent new_t+1 <= 6.
  float ptab[8];
  {
    double d = 1.0;
    const double base = (double)0.95f;
#pragma unroll
    for (int j = 0; j < 8; ++j) {
      ptab[j] = (float)d;
      d *= base;
    }
  }

  const size_t BN = (size_t)batch * kNRec;
  float* __restrict__ out_z = out;
  float* __restrict__ out_v = out + BN;
  float* __restrict__ out_t = out + 2 * BN;

#pragma unroll
  for (int i = 0; i < 4; ++i) {
#pragma unroll
    for (int hlf = 0; hlf < 2; ++hlf) {
      const size_t off = (size_t)(row0 + i) * kNRec + c0 + hlf * 64;
      const float4 vv = *reinterpret_cast<const float4*>(v + off);
      const float4 zz = *reinterpret_cast<const float4*>(z + off);
      const float4 tt = *reinterpret_cast<const float4*>(t + off);
      float oz[4], ov[4], ot[4];
#pragma unroll
      for (int c = 0; c < 4; ++c) {
        const float s = acc[i][hlf * 4 + c];           // i_in
        const bool h = (s != 0.0f);                    // h = (i_in != 0)
        const float tcur = fcomp(tt, c);
        const float ntv = h ? tcur : __fadd_rn(tcur, 1.0f);  // new_t pre-reset
        const float vcur = fcomp(vv, c);
        const float zcur = fcomp(zz, c);
        // new_v = v * (1 - z)
        float nv = __fmul_rn(vcur, __fsub_rn(1.0f, zcur));
        // clamp below -1: new_v -= (1 - (v > -1)) * (v + 1)
        const float lp = (vcur > -1.0f) ? 1.0f : 0.0f;
        nv = __fsub_rn(nv,
                       __fmul_rn(__fsub_rn(1.0f, lp), __fadd_rn(vcur, 1.0f)));
        // new_v *= decay ** (h * (new_t + 1))
        int ei = h ? (int)__fadd_rn(ntv, 1.0f) : 0;
        ei = ei < 0 ? 0 : (ei > 7 ? 7 : ei);
        nv = __fmul_rn(nv, ptab[ei]);
        // new_v += i_in
        nv = __fadd_rn(nv, s);
        // new_z = spike((new_v - THR)/THR)  <=>  new_v > THR
        oz[c] = (nv > 0.4f) ? 1.0f : 0.0f;
        ov[c] = nv;
        ot[c] = h ? 0.0f : ntv;  // new_t *= (h != 1)
      }
      *reinterpret_cast<float4*>(out_z + off) =
          make_float4(oz[0], oz[1], oz[2], oz[3]);
      *reinterpret_cast<float4*>(out_v + off) =
          make_float4(ov[0], ov[1], ov[2], ov[3]);
      *reinterpret_cast<float4*>(out_t + off) =
          make_float4(ot[0], ot[1], ot[2], ot[3]);
    }
  }
}

}  // namespace

extern "C" void kernel_launch(void* const* d_in, const int* in_sizes, int n_in,
                              void* d_out, int out_size, void* d_ws, size_t ws_size,
                              hipStream_t stream) {
  const float* x = (const float*)d_in[0];
  const float* z = (const float*)d_in[1];
  const float* v = (const float*)d_in[2];
  const float* t = (const float*)d_in[3];
  const float* w_in = (const float*)d_in[4];
  const float* w_rec = (const float*)d_in[5];
  float* out = (float*)d_out;

  const int batch = in_sizes[0] / kNIn;  // 131072
  const int blocks = batch / BR;         // 2048 blocks of 64 rows
  lif_fused<<<blocks, 256, 0, stream>>>(x, z, v, t, w_in, w_rec, out, batch);
}

// Round 4
// 2756.552 us; speedup vs baseline: 1.0972x; 1.0972x over previous
//
#include <hip/hip_runtime.h>

namespace {

constexpr int kNIn = 128;
constexpr int kNRec = 128;
constexpr int BR = 64;              // rows per block
constexpr int KC = 16;              // k-chunk staged in LDS (double-buffered)
constexpr int NCH = kNIn / KC;      // 8 chunks

__device__ __forceinline__ float fcomp(const float4 f, int i) {
  switch (i & 3) {
    case 0: return f.x;
    case 1: return f.y;
    case 2: return f.z;
    default: return f.w;
  }
}

// Async global->LDS DMA, 16B per lane. LDS dest is wave-uniform base +
// lane*16 (m104/m108), so layout must be flat-contiguous in lane order.
// Zero VGPR cost for staging -- this is what keeps us under the 128-VGPR
// cap that R3's register-staged pipeline blew (spill -> 10 GB scratch).
__device__ __forceinline__ void load_lds16(const float* g, float* l) {
  __builtin_amdgcn_global_load_lds(
      (const __attribute__((address_space(1))) void*)g,
      (__attribute__((address_space(3))) void*)l, 16, 0, 0);
}

// Block: 256 threads, tile 64 rows x 128 cols; thread tile 8 rows x 4 cols.
// 8x4 (not 4x8): halves ds_read traffic per FMA -> LDS pipe ~41 us device-
// wide, below the ~55-83 us VALU floor (R2's 4x8 was LDS-pipe-bound at
// ~82 us). Weights double-buffered in LDS via global_load_lds DMA, KC=16
// (32 KB total). Plain float4 stores: nontemporal stores measured 2.33x
// write amplification on gfx950 (R2).
// GEMM accumulates sequential-k fp32 FMA (merged x/z streams); epilogue
// uses explicit IEEE intrinsics to mirror numpy ops.
__global__ __launch_bounds__(256, 4) void lif_fused(
    const float* __restrict__ x, const float* __restrict__ z,
    const float* __restrict__ v, const float* __restrict__ t,
    const float* __restrict__ w_in, const float* __restrict__ w_rec,
    float* __restrict__ out, int batch) {
  __shared__ float swi[2][KC][kNRec];
  __shared__ float swr[2][KC][kNRec];

  const int tid = threadIdx.x;
  const int tc = tid & 31;          // 32 col groups x 4 cols = 128 cols
  const int tr = tid >> 5;          // 8 row groups x 8 rows = 64 rows
  const int row0 = blockIdx.x * BR + tr * 8;
  const int c0 = tc * 4;
  const int wv = tid >> 6;          // wave id (4 waves)
  const int ln = tid & 63;          // lane id

  float acc[8][4];
#pragma unroll
  for (int i = 0; i < 8; ++i)
#pragma unroll
    for (int c = 0; c < 4; ++c) acc[i][c] = 0.0f;

  const float4* __restrict__ x4 =
      reinterpret_cast<const float4*>(x) + (size_t)row0 * (kNIn / 4);
  const float4* __restrict__ z4 =
      reinterpret_cast<const float4*>(z) + (size_t)row0 * (kNRec / 4);

  // ---- DMA chunk 0 -> buffer 0 ----
  {
#pragma unroll
    for (int c = 0; c < 2; ++c) {
      const int f4 = wv * 128 + c * 64;  // wave-uniform float4 index
      load_lds16(w_in + (size_t)(f4 + ln) * 4, &swi[0][0][0] + (size_t)f4 * 4);
      load_lds16(w_rec + (size_t)(f4 + ln) * 4, &swr[0][0][0] + (size_t)f4 * 4);
    }
  }
  __syncthreads();  // drains DMA (vmcnt) + sync

  for (int ch = 0; ch < NCH; ++ch) {
    const int p = ch & 1;
    // Issue DMA for the next chunk into the other buffer; this chunk's
    // ~2048 VALU cycles cover the latency. Safe: buffer p^1's readers
    // (chunk ch-1) all passed the barrier that opened chunk ch.
    if (ch + 1 < NCH) {
      const float* gi = w_in + (size_t)(ch + 1) * KC * kNRec;
      const float* gr = w_rec + (size_t)(ch + 1) * KC * kNRec;
      float* li = &swi[p ^ 1][0][0];
      float* lr = &swr[p ^ 1][0][0];
#pragma unroll
      for (int c = 0; c < 2; ++c) {
        const int f4 = wv * 128 + c * 64;
        load_lds16(gi + (size_t)(f4 + ln) * 4, li + (size_t)f4 * 4);
        load_lds16(gr + (size_t)(f4 + ln) * 4, lr + (size_t)f4 * 4);
      }
    }

#pragma unroll
    for (int kq = 0; kq < KC / 4; ++kq) {
      const int kg = ch * (KC / 4) + kq;  // global k-quad
      float4 ax[8], az[8];
#pragma unroll
      for (int i = 0; i < 8; ++i) {
        ax[i] = x4[i * (kNIn / 4) + kg];   // x and z share one offset set
        az[i] = z4[i * (kNRec / 4) + kg];  // (same row stride, same kg)
      }
#pragma unroll
      for (int kk = 0; kk < 4; ++kk) {
        const int k = kq * 4 + kk;
        const float4 wi0 = *reinterpret_cast<const float4*>(&swi[p][k][c0]);
        const float4 wr0 = *reinterpret_cast<const float4*>(&swr[p][k][c0]);
#pragma unroll
        for (int i = 0; i < 8; ++i) {
          const float a = fcomp(ax[i], kk);
          const float b = fcomp(az[i], kk);
          acc[i][0] = __fmaf_rn(a, wi0.x, acc[i][0]);
          acc[i][1] = __fmaf_rn(a, wi0.y, acc[i][1]);
          acc[i][2] = __fmaf_rn(a, wi0.z, acc[i][2]);
          acc[i][3] = __fmaf_rn(a, wi0.w, acc[i][3]);
          acc[i][0] = __fmaf_rn(b, wr0.x, acc[i][0]);
          acc[i][1] = __fmaf_rn(b, wr0.y, acc[i][1]);
          acc[i][2] = __fmaf_rn(b, wr0.z, acc[i][2]);
          acc[i][3] = __fmaf_rn(b, wr0.w, acc[i][3]);
        }
      }
    }
    if (ch + 1 < NCH) __syncthreads();  // DMA drained; buffers swap
  }

  // decay powers 0.95^e, e in [1,5] (t in [0,4] -> exponent new_t+1 <= 5),
  // computed exactly in double then rounded once -- compile-time folded.
  // Branchless select chain (no runtime-indexed local array -> no scratch).
  const double bd = (double)0.95f;
  const float P1 = (float)bd;
  const float P2 = (float)(bd * bd);
  const float P3 = (float)(bd * bd * bd);
  const float P4 = (float)(bd * bd * bd * bd);
  const float P5 = (float)(bd * bd * bd * bd * bd);

  const size_t BN = (size_t)batch * kNRec;
  float* __restrict__ out_z = out;
  float* __restrict__ out_v = out + BN;
  float* __restrict__ out_t = out + 2 * BN;

#pragma unroll
  for (int i = 0; i < 8; ++i) {
    const size_t off = (size_t)(row0 + i) * kNRec + c0;
    const float4 vv = *reinterpret_cast<const float4*>(v + off);
    const float4 zz = *reinterpret_cast<const float4*>(z + off);
    const float4 tt = *reinterpret_cast<const float4*>(t + off);
    float oz[4], ov[4], ot[4];
#pragma unroll
    for (int c = 0; c < 4; ++c) {
      const float s = acc[i][c];                     // i_in
      const bool h = (s != 0.0f);                    // h = (i_in != 0)
      const float tcur = fcomp(tt, c);
      const float ntv = h ? tcur : __fadd_rn(tcur, 1.0f);  // new_t pre-reset
      const float vcur = fcomp(vv, c);
      const float zcur = fcomp(zz, c);
      // new_v = v * (1 - z)
      float nv = __fmul_rn(vcur, __fsub_rn(1.0f, zcur));
      // clamp below -1: new_v -= (1 - (v > -1)) * (v + 1)
      const float lp = (vcur > -1.0f) ? 1.0f : 0.0f;
      nv = __fsub_rn(nv,
                     __fmul_rn(__fsub_rn(1.0f, lp), __fadd_rn(vcur, 1.0f)));
      // new_v *= decay ** (h * (new_t + 1)); exponent = h ? t+1 : 0
      const float pw = (tcur < 0.5f)   ? P1
                       : (tcur < 1.5f) ? P2
                       : (tcur < 2.5f) ? P3
                       : (tcur < 3.5f) ? P4
                                       : P5;
      nv = __fmul_rn(nv, h ? pw : 1.0f);
      // new_v += i_in
      nv = __fadd_rn(nv, s);
      // new_z = spike((new_v - THR)/THR)  <=>  new_v > THR
      oz[c] = (nv > 0.4f) ? 1.0f : 0.0f;
      ov[c] = nv;
      ot[c] = h ? 0.0f : ntv;  // new_t *= (h != 1)
    }
    *reinterpret_cast<float4*>(out_z + off) =
        make_float4(oz[0], oz[1], oz[2], oz[3]);
    *reinterpret_cast<float4*>(out_v + off) =
        make_float4(ov[0], ov[1], ov[2], ov[3]);
    *reinterpret_cast<float4*>(out_t + off) =
        make_float4(ot[0], ot[1], ot[2], ot[3]);
  }
}

}  // namespace

extern "C" void kernel_launch(void* const* d_in, const int* in_sizes, int n_in,
                              void* d_out, int out_size, void* d_ws, size_t ws_size,
                              hipStream_t stream) {
  const float* x = (const float*)d_in[0];
  const float* z = (const float*)d_in[1];
  const float* v = (const float*)d_in[2];
  const float* t = (const float*)d_in[3];
  const float* w_in = (const float*)d_in[4];
  const float* w_rec = (const float*)d_in[5];
  float* out = (float*)d_out;

  const int batch = in_sizes[0] / kNIn;  // 131072
  const int blocks = batch / BR;         // 2048 blocks of 64 rows
  lif_fused<<<blocks, 256, 0, stream>>>(x, z, v, t, w_in, w_rec, out, batch);
}